// Round 9
// baseline (278.560 us; speedup 1.0000x reference)
//
#include <hip/hip_runtime.h>
#include <hip/hip_bf16.h>
#include <stdint.h>

#define B_ROWS 4096
#define D_K    256
#define Q_ROWS 65536
#define HALF   2048

typedef __bf16 bf16x8 __attribute__((ext_vector_type(8)));
typedef float  f32x4  __attribute__((ext_vector_type(4)));
typedef int    v8i    __attribute__((ext_vector_type(8)));
typedef int    v4i    __attribute__((ext_vector_type(4)));
typedef unsigned short u16x8 __attribute__((ext_vector_type(8)));
typedef const __attribute__((address_space(1))) void* gptr1;
typedef __attribute__((address_space(3))) void* lptr3;

__device__ __forceinline__ unsigned int f32_ordered(float f) {
    unsigned int u = __float_as_uint(f);
    return (u & 0x80000000u) ? ~u : (u | 0x80000000u);
}

__device__ __forceinline__ unsigned short f2bf_rn(float f) {
    unsigned int u = __float_as_uint(f);
    u += 0x7FFFu + ((u >> 16) & 1u);
    return (unsigned short)(u >> 16);
}

// ---------- fused prep: emb/queue -> fp8 e4m3, preds -> bf16, zero amax/out ----------
// R18 body: 16 elements/thread, int4 stores for fp8, ushort8 stores for bf16.
#define EMB4  (B_ROWS * D_K / 4)          // 262144 granules
#define PRED4 (B_ROWS * D_K / 4)          // 262144
#define QUE4  (Q_ROWS * D_K / 4)          // 4194304
#define PREP_THREADS ((EMB4 + PRED4 + QUE4) / 4)   // 1179648
__global__ __launch_bounds__(256) void prep_kernel(const float* __restrict__ emb,
                                                   const float* __restrict__ preds,
                                                   const float* __restrict__ queue,
                                                   unsigned char* __restrict__ emb8,
                                                   unsigned short* __restrict__ preds_bf,
                                                   unsigned char* __restrict__ queue8,
                                                   unsigned long long* __restrict__ amax,
                                                   float* __restrict__ out) {
    const int t  = blockIdx.x * 256 + threadIdx.x;
    const int g0 = t * 4;                 // first granule (4 floats each)
    if (g0 < EMB4) {
        const float4* src = (const float4*)emb + g0;
        int4 o;
        { float4 v = src[0]; int u = __builtin_amdgcn_cvt_pk_fp8_f32(v.x, v.y, 0, false);
          o.x = __builtin_amdgcn_cvt_pk_fp8_f32(v.z, v.w, u, true); }
        { float4 v = src[1]; int u = __builtin_amdgcn_cvt_pk_fp8_f32(v.x, v.y, 0, false);
          o.y = __builtin_amdgcn_cvt_pk_fp8_f32(v.z, v.w, u, true); }
        { float4 v = src[2]; int u = __builtin_amdgcn_cvt_pk_fp8_f32(v.x, v.y, 0, false);
          o.z = __builtin_amdgcn_cvt_pk_fp8_f32(v.z, v.w, u, true); }
        { float4 v = src[3]; int u = __builtin_amdgcn_cvt_pk_fp8_f32(v.x, v.y, 0, false);
          o.w = __builtin_amdgcn_cvt_pk_fp8_f32(v.z, v.w, u, true); }
        ((int4*)emb8)[t] = o;
    } else if (g0 < EMB4 + PRED4) {
        const int off = g0 - EMB4;        // granule offset, divisible by 4
        const float4* src = (const float4*)preds + off;
#pragma unroll
        for (int h = 0; h < 2; h++) {
            float4 v0 = src[2 * h], v1 = src[2 * h + 1];
            u16x8 o;
            o[0] = f2bf_rn(v0.x); o[1] = f2bf_rn(v0.y); o[2] = f2bf_rn(v0.z); o[3] = f2bf_rn(v0.w);
            o[4] = f2bf_rn(v1.x); o[5] = f2bf_rn(v1.y); o[6] = f2bf_rn(v1.z); o[7] = f2bf_rn(v1.w);
            ((u16x8*)preds_bf)[(off >> 1) + h] = o;
        }
    } else {
        const int off = g0 - EMB4 - PRED4;
        const float4* src = (const float4*)queue + off;
        int4 o;
        { float4 v = src[0]; int u = __builtin_amdgcn_cvt_pk_fp8_f32(v.x, v.y, 0, false);
          o.x = __builtin_amdgcn_cvt_pk_fp8_f32(v.z, v.w, u, true); }
        { float4 v = src[1]; int u = __builtin_amdgcn_cvt_pk_fp8_f32(v.x, v.y, 0, false);
          o.y = __builtin_amdgcn_cvt_pk_fp8_f32(v.z, v.w, u, true); }
        { float4 v = src[2]; int u = __builtin_amdgcn_cvt_pk_fp8_f32(v.x, v.y, 0, false);
          o.z = __builtin_amdgcn_cvt_pk_fp8_f32(v.z, v.w, u, true); }
        { float4 v = src[3]; int u = __builtin_amdgcn_cvt_pk_fp8_f32(v.x, v.y, 0, false);
          o.w = __builtin_amdgcn_cvt_pk_fp8_f32(v.z, v.w, u, true); }
        ((int4*)queue8)[off >> 2] = o;
    }
    if (t < B_ROWS) amax[t] = 0ull;   // ordered-float 0 == below every real value
    if (t == 0) out[0] = 0.f;
}

// ---------- fused sim GEMM + row argmax, MX-fp8 (scale=1.0) ----------
// R19: bufferless-B. R16's phase accounting shows LDS ~72% busy per CU
// (64 ds_read_b128 + 32KB staging + conflicts vs 1600cy wall) and barrier
// lockstep on top. Fix: B fragments load straight global->VGPR. The per-XCD
// B working set is 2MB (XCD swizzle pins 8 n-groups/XCD) -> L2-resident;
// demand ~59 B/cyc/CU << 135 B/cyc L2 ceiling; L1 catches the 2x intra-block
// re-read. The MFMA B fragment is just 32 contiguous bytes
// queue8[col*256 + kt*128 + quad*32] (verified against the R16 swizzle
// algebra) -> 2x global_load_dwordx4. This DELETES: all K-loop barriers
// (waves free-run, no lockstep), the LDS ring + vmcnt discipline, all LDS-B
// traffic. Two named reg buffers (b0=kt0, b1=kt1, 32 VGPR each) keep every
// load >=550cy in flight vs ~250cy L2 latency. Ledger ~233 VGPR < 256 cap
// of launch_bounds(256,2) [pinned by R13/R15]. LDS now 32KB (A prologue only).
#define BM 128
#define BN 128
#define NCHUNK 8
#define MFMA_FP8(av, bv, c) \
    __builtin_amdgcn_mfma_scale_f32_16x16x128_f8f6f4((av), (bv), (c), 0, 0, 0, 0x7F7F7F7F, 0, 0x7F7F7F7F)

__global__ __launch_bounds__(256, 2) void sim_argmax_kernel(const unsigned char* __restrict__ A8,
                                                            const unsigned char* __restrict__ B8,
                                                            unsigned long long* __restrict__ amax) {
    __shared__ unsigned char sh[32768];   // A tile only

    const int tid  = threadIdx.x;
    const int wave = tid >> 6;          // 0..3
    const int lane = tid & 63;
    const int l15  = lane & 15;
    const int quad = lane >> 4;

    // XCD-aware swizzle: block i -> XCD i%8 (dispatch heuristic).
    const int bid  = blockIdx.x;
    const int xcd  = bid & 7;
    const int j    = bid >> 3;
    const int blk_m = (j & 31) * BM;
    const int ngrp  = (j >> 5) * 8 + xcd;
    const int nbase = ngrp * (BN * NCHUNK);

    const int wave_m = (wave >> 1) * 64;
    const int wave_n = (wave & 1) * 64;

    // ---- prologue: stage A (32 KB) into sh, swizzled: LDS byte j*4096 + tid*16
    // holds row r = j*16 + (tid>>4), slot tid&15; global granule g = slot ^ (r&15).
    {
        const unsigned char* gA = A8 + (size_t)(blk_m + (tid >> 4)) * D_K
                                     + (((tid & 15) ^ ((tid >> 4) & 15)) << 4);
#pragma unroll
        for (int jj = 0; jj < 8; jj++)
            __builtin_amdgcn_global_load_lds((gptr1)(gA + jj * 4096),
                                             (lptr3)&sh[jj * 4096 + wave * 1024], 16, 0, 0);
    }
    __syncthreads();   // A resident in LDS

    // read A fragments into registers: areg[kt][mi], 8 x v8i = 64 VGPRs
    const int pA = (quad * 2) ^ l15;          // slot of A lo-granule for kt=0
    v8i areg[2][4];
#pragma unroll
    for (int kt = 0; kt < 2; kt++) {
#pragma unroll
        for (int mi = 0; mi < 4; mi++) {
            const int _lo = (wave_m + mi * 16 + l15) * 256 + ((pA ^ (kt << 3)) << 4);
            v4i _x = *(const v4i*)&sh[_lo];
            v4i _y = *(const v4i*)&sh[_lo ^ 16];
            areg[kt][mi] = __builtin_shufflevector(_x, _y, 0, 1, 2, 3, 4, 5, 6, 7);
        }
    }
    // sh never reused; no second barrier, no sleep — waves free-run from here.

    // ---- per-lane B base pointers: this lane's column for ni is
    // nbase + wave_n + ni*16 + l15; fragment kt at byte col*256 + kt*128 + quad*32.
    const unsigned char* bptr0 = B8 + (size_t)(nbase + wave_n + l15) * 256 + quad * 32;
    const unsigned char* bptr[4];
#pragma unroll
    for (int ni = 0; ni < 4; ni++) bptr[ni] = bptr0 + ni * 16 * 256;

    int bestk[4][4];                          // packed (value&~31 | slot) keys
#pragma unroll
    for (int mi = 0; mi < 4; mi++)
#pragma unroll
        for (int reg = 0; reg < 4; reg++) bestk[mi][reg] = 0x80000000;   // INT_MIN

    f32x4 acc[4][4];
    const f32x4 zero4 = (f32x4){0.f, 0.f, 0.f, 0.f};

    v4i b0[8], b1[8];                         // kt0 / kt1 fragment buffers

#define LOADH(BUF, KT) do {                                                            \
        _Pragma("unroll")                                                              \
        for (int ni = 0; ni < 4; ni++) {                                               \
            BUF[2 * ni]     = *(const v4i*)(bptr[ni] + (KT) * 128);                    \
            BUF[2 * ni + 1] = *(const v4i*)(bptr[ni] + (KT) * 128 + 16);               \
        }                                                                              \
    } while (0)

#define ADVB() do {                                                                    \
        _Pragma("unroll")                                                              \
        for (int ni = 0; ni < 4; ni++) bptr[ni] += BN * D_K;   /* next chunk */        \
    } while (0)

// K lo half: fresh accumulate (zero C operand -> no reset movs needed)
#define COMPUTE0(BUF) do {                                                             \
        __builtin_amdgcn_s_setprio(1);                                                 \
        _Pragma("unroll")                                                              \
        for (int ni = 0; ni < 4; ni++) {                                               \
            v8i bv = __builtin_shufflevector(BUF[2 * ni], BUF[2 * ni + 1],             \
                                             0, 1, 2, 3, 4, 5, 6, 7);                  \
            _Pragma("unroll")                                                          \
            for (int mi = 0; mi < 4; mi++)                                             \
                acc[mi][ni] = MFMA_FP8(areg[0][mi], bv, zero4);                        \
        }                                                                              \
        __builtin_amdgcn_s_setprio(0);                                                 \
    } while (0)

// K hi half: chain on lo half
#define COMPUTE1(BUF) do {                                                             \
        __builtin_amdgcn_s_setprio(1);                                                 \
        _Pragma("unroll")                                                              \
        for (int ni = 0; ni < 4; ni++) {                                               \
            v8i bv = __builtin_shufflevector(BUF[2 * ni], BUF[2 * ni + 1],             \
                                             0, 1, 2, 3, 4, 5, 6, 7);                  \
            _Pragma("unroll")                                                          \
            for (int mi = 0; mi < 4; mi++)                                             \
                acc[mi][ni] = MFMA_FP8(areg[1][mi], bv, acc[mi][ni]);                  \
        }                                                                              \
        __builtin_amdgcn_s_setprio(0);                                                 \
    } while (0)

// fold chunk PP's acc into packed keys: v_and_or_b32 + v_max_i32 per element
#define FOLDK(PP) do {                                                                 \
        _Pragma("unroll")                                                              \
        for (int ni = 0; ni < 4; ni++) {                                               \
            const int _slot = 31 - ((PP) * 4 + ni);   /* bigger key = smaller col */   \
            _Pragma("unroll")                                                          \
            for (int mi = 0; mi < 4; mi++)                                             \
                _Pragma("unroll")                                                      \
                for (int reg = 0; reg < 4; reg++) {                                    \
                    int ik = (__float_as_int(acc[mi][ni][reg]) & 0xFFFFFFE0) | _slot;  \
                    bestk[mi][reg] = max(bestk[mi][reg], ik);                          \
                }                                                                      \
        }                                                                              \
    } while (0)

    LOADH(b0, 0);                             // prologue: chunk 0 kt0 in flight

#pragma unroll 1
    for (int p = 0; p < NCHUNK; ++p) {
        LOADH(b1, 1);                         // issue chunk p kt1 loads
        if (p > 0) FOLDK(p - 1);              // fold prev chunk (WAR vs COMPUTE0)
        COMPUTE0(b0);                         // chunk p, K[0:128)  (loaded 1 iter ago)
        ADVB();                               // bptr -> chunk p+1
        if (p < NCHUNK - 1) LOADH(b0, 0);     // issue chunk p+1 kt0 loads
        COMPUTE1(b1);                         // chunk p, K[128:256)
    }
    FOLDK(NCHUNK - 1);                        // last chunk

    // Epilogue (once per block): decode keys, 16-lane reduce, one atomic per slot
#pragma unroll
    for (int mi = 0; mi < 4; mi++) {
#pragma unroll
        for (int reg = 0; reg < 4; reg++) {
            unsigned u     = (unsigned)bestk[mi][reg];
            unsigned vbits = u & 0xFFFFFFE0u;
            int      pni   = 31 - (int)(u & 31u);
            int      col   = nbase + (pni >> 2) * BN + wave_n + ((pni & 3) << 4) + l15;
            unsigned ov    = (vbits & 0x80000000u) ? ~vbits : (vbits | 0x80000000u);
            unsigned long long key =
                ((unsigned long long)ov << 32) |
                (unsigned long long)(0xFFFFFFFFu - (unsigned)col);   // ~col: ties -> smaller col
#pragma unroll
            for (int m = 1; m < 16; m <<= 1) {
                unsigned long long o = __shfl_xor(key, m, 16);
                if (o > key) key = o;
            }
            if (l15 == mi * 4 + reg) {
                int row = blk_m + wave_m + mi * 16 + quad * 4 + reg;
                atomicMax(&amax[row], key);
            }
        }
    }
}

// ---------- logits + online logsumexp - diag + final reduce ----------
// R18 body: two independent 4-deep MFMA chains per tile.
__global__ __launch_bounds__(512) void logits_ce_kernel(const unsigned long long* __restrict__ amax,
                                                        const float* __restrict__ queue_f32,
                                                        const unsigned short* __restrict__ preds_bf,
                                                        float* __restrict__ out) {
    const int gw   = blockIdx.x;        // 0..255 (16-row group)
    const int tid  = threadIdx.x;
    const int wave = tid >> 6;          // 0..7
    const int lane = tid & 63;
    const int l15  = lane & 15;
    const int quad = lane >> 4;
    const int h    = gw >> 7;           // 0: ab, 1: ba
    const int rowbase = gw * 16;
    const unsigned short* Bbase = preds_bf + (size_t)((1 - h) * HALF) * D_K;

    __shared__ float sm[8][16], sl[8][16], sd[8][16];

    // inline gather from fp32 queue: this lane's A-row = queue[argmax(rowbase+l15)]
    unsigned idx = 0xFFFFFFFFu - (unsigned)(amax[rowbase + l15] & 0xFFFFFFFFull);
    const float* arow = queue_f32 + (size_t)idx * D_K;
    bf16x8 a[8];
#pragma unroll
    for (int kc = 0; kc < 8; kc++) {
        float4 f0 = *(const float4*)(arow + kc * 32 + quad * 8);
        float4 f1 = *(const float4*)(arow + kc * 32 + quad * 8 + 4);
        u16x8 t;
        t[0] = f2bf_rn(f0.x); t[1] = f2bf_rn(f0.y); t[2] = f2bf_rn(f0.z); t[3] = f2bf_rn(f0.w);
        t[4] = f2bf_rn(f1.x); t[5] = f2bf_rn(f1.y); t[6] = f2bf_rn(f1.z); t[7] = f2bf_rn(f1.w);
        a[kc] = *(const bf16x8*)&t;
    }

    float m_run[4], l_run[4], diag[4];
#pragma unroll
    for (int r = 0; r < 4; r++) { m_run[r] = -1e30f; l_run[r] = 0.f; diag[r] = -1e30f; }

    const int tdiag = gw & 127;
    for (int tt = 0; tt < 16; tt++) {
        const int t = wave * 16 + tt;
        f32x4 acc0 = (f32x4){0.f, 0.f, 0.f, 0.f};
        f32x4 acc1 = (f32x4){0.f, 0.f, 0.f, 0.f};
#pragma unroll
        for (int kc = 0; kc < 4; kc++) {
            bf16x8 b0 = *(const bf16x8*)&Bbase[(size_t)(t * 16 + l15) * D_K + kc * 32 + quad * 8];
            acc0 = __builtin_amdgcn_mfma_f32_16x16x32_bf16(a[kc], b0, acc0, 0, 0, 0);
            bf16x8 b1 = *(const bf16x8*)&Bbase[(size_t)(t * 16 + l15) * D_K + (kc + 4) * 32 + quad * 8];
            acc1 = __builtin_amdgcn_mfma_f32_16x16x32_bf16(a[kc + 4], b1, acc1, 0, 0, 0);
        }
        f32x4 acc = acc0 + acc1;
#pragma unroll
        for (int reg = 0; reg < 4; reg++) {
            float v = acc[reg] * 10.0f;              // 1/TEMPERATURE
            if (t == tdiag && l15 == quad * 4 + reg) diag[reg] = v;
            float nm = fmaxf(m_run[reg], v);
            l_run[reg] = l_run[reg] * __expf(m_run[reg] - nm) + __expf(v - nm);
            m_run[reg] = nm;
        }
    }
    // 16-lane merge within the wave
#pragma unroll
    for (int reg = 0; reg < 4; reg++) {
#pragma unroll
        for (int m = 1; m < 16; m <<= 1) {
            float om = __shfl_xor(m_run[reg], m, 16);
            float ol = __shfl_xor(l_run[reg], m, 16);
            float od = __shfl_xor(diag[reg], m, 16);
            float nm = fmaxf(m_run[reg], om);
            l_run[reg] = l_run[reg] * __expf(m_run[reg] - nm) + ol * __expf(om - nm);
            m_run[reg] = nm;
            diag[reg] = fmaxf(diag[reg], od);
        }
        if (l15 == 0) {
            sm[wave][quad * 4 + reg] = m_run[reg];
            sl[wave][quad * 4 + reg] = l_run[reg];
            sd[wave][quad * 4 + reg] = diag[reg];
        }
    }
    __syncthreads();
    // cross-wave merge + block-local reduce + single atomic into out
    if (tid < 16) {
        float M = -1e30f, L = 0.f, Dg = -1e30f;
#pragma unroll
        for (int w = 0; w < 8; w++) {
            float mw = sm[w][tid], lw = sl[w][tid], dw = sd[w][tid];
            float nM = fmaxf(M, mw);
            L = L * __expf(M - nM) + lw * __expf(mw - nM);
            M = nM;
            Dg = fmaxf(Dg, dw);
        }
        float rl = (M + __logf(L)) - Dg;
#pragma unroll
        for (int m = 1; m < 16; m <<= 1) rl += __shfl_xor(rl, m, 16);
        if (tid == 0) atomicAdd(out, rl * (1.0f / (float)B_ROWS));
    }
}

extern "C" void kernel_launch(void* const* d_in, const int* in_sizes, int n_in,
                              void* d_out, int out_size, void* d_ws, size_t ws_size,
                              hipStream_t stream) {
    const float* emb   = (const float*)d_in[0];
    const float* preds = (const float*)d_in[1];
    const float* queue = (const float*)d_in[2];

    char* w = (char*)d_ws;
    unsigned long long* amax  = (unsigned long long*)w;                     // 32 KB
    unsigned char*  emb8      = (unsigned char*)(w + (1u << 20));           // 1 MB
    unsigned short* preds_bf  = (unsigned short*)(w + (2u << 20));          // 2 MB
    unsigned char*  queue8    = (unsigned char*)(w + (4u << 20));           // 16 MB

    prep_kernel<<<dim3(PREP_THREADS / 256), 256, 0, stream>>>(
        emb, preds, queue, emb8, preds_bf, queue8, amax, (float*)d_out);
    sim_argmax_kernel<<<dim3((B_ROWS / BM) * (Q_ROWS / (BN * NCHUNK))), 256, 0, stream>>>(
        emb8, queue8, amax);
    logits_ce_kernel<<<dim3(B_ROWS / 16), 512, 0, stream>>>(
        amax, queue, preds_bf, (float*)d_out);
}

// Round 10
// 197.076 us; speedup vs baseline: 1.4135x; 1.4135x over previous
//
#include <hip/hip_runtime.h>
#include <hip/hip_bf16.h>
#include <stdint.h>

#define B_ROWS 4096
#define D_K    256
#define Q_ROWS 65536
#define HALF   2048

typedef __bf16 bf16x8 __attribute__((ext_vector_type(8)));
typedef float  f32x4  __attribute__((ext_vector_type(4)));
typedef int    v8i    __attribute__((ext_vector_type(8)));
typedef int    v4i    __attribute__((ext_vector_type(4)));
typedef unsigned short u16x8 __attribute__((ext_vector_type(8)));
typedef const __attribute__((address_space(1))) void* gptr1;
typedef __attribute__((address_space(3))) void* lptr3;

__device__ __forceinline__ unsigned int f32_ordered(float f) {
    unsigned int u = __float_as_uint(f);
    return (u & 0x80000000u) ? ~u : (u | 0x80000000u);
}

__device__ __forceinline__ unsigned short f2bf_rn(float f) {
    unsigned int u = __float_as_uint(f);
    u += 0x7FFFu + ((u >> 16) & 1u);
    return (unsigned short)(u >> 16);
}

// ---------- fused prep: emb/queue -> fp8 e4m3, preds -> bf16, zero amax/out ----------
// R18 body: 16 elements/thread, int4 stores for fp8, ushort8 stores for bf16.
#define EMB4  (B_ROWS * D_K / 4)          // 262144 granules
#define PRED4 (B_ROWS * D_K / 4)          // 262144
#define QUE4  (Q_ROWS * D_K / 4)          // 4194304
#define PREP_THREADS ((EMB4 + PRED4 + QUE4) / 4)   // 1179648
__global__ __launch_bounds__(256) void prep_kernel(const float* __restrict__ emb,
                                                   const float* __restrict__ preds,
                                                   const float* __restrict__ queue,
                                                   unsigned char* __restrict__ emb8,
                                                   unsigned short* __restrict__ preds_bf,
                                                   unsigned char* __restrict__ queue8,
                                                   unsigned long long* __restrict__ amax,
                                                   float* __restrict__ out) {
    const int t  = blockIdx.x * 256 + threadIdx.x;
    const int g0 = t * 4;                 // first granule (4 floats each)
    if (g0 < EMB4) {
        const float4* src = (const float4*)emb + g0;
        int4 o;
        { float4 v = src[0]; int u = __builtin_amdgcn_cvt_pk_fp8_f32(v.x, v.y, 0, false);
          o.x = __builtin_amdgcn_cvt_pk_fp8_f32(v.z, v.w, u, true); }
        { float4 v = src[1]; int u = __builtin_amdgcn_cvt_pk_fp8_f32(v.x, v.y, 0, false);
          o.y = __builtin_amdgcn_cvt_pk_fp8_f32(v.z, v.w, u, true); }
        { float4 v = src[2]; int u = __builtin_amdgcn_cvt_pk_fp8_f32(v.x, v.y, 0, false);
          o.z = __builtin_amdgcn_cvt_pk_fp8_f32(v.z, v.w, u, true); }
        { float4 v = src[3]; int u = __builtin_amdgcn_cvt_pk_fp8_f32(v.x, v.y, 0, false);
          o.w = __builtin_amdgcn_cvt_pk_fp8_f32(v.z, v.w, u, true); }
        ((int4*)emb8)[t] = o;
    } else if (g0 < EMB4 + PRED4) {
        const int off = g0 - EMB4;        // granule offset, divisible by 4
        const float4* src = (const float4*)preds + off;
#pragma unroll
        for (int h = 0; h < 2; h++) {
            float4 v0 = src[2 * h], v1 = src[2 * h + 1];
            u16x8 o;
            o[0] = f2bf_rn(v0.x); o[1] = f2bf_rn(v0.y); o[2] = f2bf_rn(v0.z); o[3] = f2bf_rn(v0.w);
            o[4] = f2bf_rn(v1.x); o[5] = f2bf_rn(v1.y); o[6] = f2bf_rn(v1.z); o[7] = f2bf_rn(v1.w);
            ((u16x8*)preds_bf)[(off >> 1) + h] = o;
        }
    } else {
        const int off = g0 - EMB4 - PRED4;
        const float4* src = (const float4*)queue + off;
        int4 o;
        { float4 v = src[0]; int u = __builtin_amdgcn_cvt_pk_fp8_f32(v.x, v.y, 0, false);
          o.x = __builtin_amdgcn_cvt_pk_fp8_f32(v.z, v.w, u, true); }
        { float4 v = src[1]; int u = __builtin_amdgcn_cvt_pk_fp8_f32(v.x, v.y, 0, false);
          o.y = __builtin_amdgcn_cvt_pk_fp8_f32(v.z, v.w, u, true); }
        { float4 v = src[2]; int u = __builtin_amdgcn_cvt_pk_fp8_f32(v.x, v.y, 0, false);
          o.z = __builtin_amdgcn_cvt_pk_fp8_f32(v.z, v.w, u, true); }
        { float4 v = src[3]; int u = __builtin_amdgcn_cvt_pk_fp8_f32(v.x, v.y, 0, false);
          o.w = __builtin_amdgcn_cvt_pk_fp8_f32(v.z, v.w, u, true); }
        ((int4*)queue8)[off >> 2] = o;
    }
    if (t < B_ROWS) amax[t] = 0ull;   // ordered-float 0 == below every real value
    if (t == 0) out[0] = 0.f;
}

// ---------- fused sim GEMM + row argmax, MX-fp8 (scale=1.0) ----------
// R20: proven R14/R16 body (launch_bounds(256,2) PINNED [1->collapse R13,
// 3->spill R15]; 16x16x128 PINNED [32x32 hurt, R17]; LDS-staged B PINNED
// [direct global-B = 16-way divergent loads, R19]; 3-buffer ring + counted
// vmcnt(4); packed-key deferred fold; zero-C) with two amortization changes:
//  - anti-phase sleep REMOVED (proven null R16, costs ~1-2us).
//  - NCHUNK 8 -> 16: grid 2048 -> 1024, block-rounds/CU 8 -> 4. Halves the
//    recurring per-block fixed costs (A-stage prologue + areg read ~2000cy,
//    ring fill/drain, epilogue reduce + atomics). Packed-key slot widens to
//    6 bits; masked tie-window 64 ulp (~1.2e-4) still far below the fp8
//    quantization granularity that governs argmax (5-bit passed 5 runs).
#define BM 128
#define BN 128
#define NCHUNK 16
#define MFMA_FP8(av, bv, c) \
    __builtin_amdgcn_mfma_scale_f32_16x16x128_f8f6f4((av), (bv), (c), 0, 0, 0, 0x7F7F7F7F, 0, 0x7F7F7F7F)

#define WAITV(N) asm volatile("s_waitcnt vmcnt(" #N ")" ::: "memory")
#define BARRIER() do { __builtin_amdgcn_s_barrier(); \
                       asm volatile("" ::: "memory"); \
                       __builtin_amdgcn_sched_barrier(0); } while (0)

__global__ __launch_bounds__(256, 2) void sim_argmax_kernel(const unsigned char* __restrict__ A8,
                                                            const unsigned char* __restrict__ B8,
                                                            unsigned long long* __restrict__ amax) {
    __shared__ unsigned char sh[49152];   // phase 1: A tile (32 KB); phase 2: B ring (3 x 16 KB)

    const int tid  = threadIdx.x;
    const int wave = tid >> 6;          // 0..3
    const int lane = tid & 63;
    const int l15  = lane & 15;
    const int quad = lane >> 4;

    // XCD-aware swizzle: block i -> XCD i%8 (dispatch heuristic).
    const int bid  = blockIdx.x;
    const int xcd  = bid & 7;
    const int j    = bid >> 3;
    const int blk_m = (j & 31) * BM;
    const int ngrp  = (j >> 5) * 8 + xcd;         // 0..31
    const int nbase = ngrp * (BN * NCHUNK);

    const int wave_m = (wave >> 1) * 64;
    const int wave_n = (wave & 1) * 64;

    // ---- phase 1: stage A (32 KB) into sh, swizzled: LDS byte j*4096 + tid*16
    // holds row r = j*16 + (tid>>4), slot tid&15; global granule g = slot ^ (r&15).
    {
        const unsigned char* gA = A8 + (size_t)(blk_m + (tid >> 4)) * D_K
                                     + (((tid & 15) ^ ((tid >> 4) & 15)) << 4);
#pragma unroll
        for (int jj = 0; jj < 8; jj++)
            __builtin_amdgcn_global_load_lds((gptr1)(gA + jj * 4096),
                                             (lptr3)&sh[jj * 4096 + wave * 1024], 16, 0, 0);
    }
    __syncthreads();   // A resident in LDS

    // read A fragments into registers: areg[kt][mi], 8 x v8i = 64 VGPRs
    const int pA = (quad * 2) ^ l15;          // slot of A lo-granule for kt=0
    v8i areg[2][4];
#pragma unroll
    for (int kt = 0; kt < 2; kt++) {
#pragma unroll
        for (int mi = 0; mi < 4; mi++) {
            const int _lo = (wave_m + mi * 16 + l15) * 256 + ((pA ^ (kt << 3)) << 4);
            v4i _x = *(const v4i*)&sh[_lo];
            v4i _y = *(const v4i*)&sh[_lo ^ 16];
            areg[kt][mi] = __builtin_shufflevector(_x, _y, 0, 1, 2, 3, 4, 5, 6, 7);
        }
    }
    __syncthreads();   // all lanes done reading A; sh becomes the B ring

    // ---- B staging base: issue j covers rows j*32 + (tid>>3), slot tid&7,
    // global granule g = slot ^ (r&7). Tile T: +(T>>1)*32768 + (T&1)*128 bytes.
    const unsigned char* gB = B8 + (size_t)(nbase + (tid >> 3)) * D_K
                                 + (((tid & 7) ^ ((tid >> 3) & 7)) << 4);

#define PREFB(T, BSOFF) do {                                                           \
        const int _off = ((T) >> 1) * (32 * D_K * 4) + ((T) & 1) * 128;                \
        _Pragma("unroll")                                                              \
        for (int _j = 0; _j < 4; _j++)                                                 \
            __builtin_amdgcn_global_load_lds((gptr1)(gB + _j * 8192 + _off),           \
                                             (lptr3)&sh[(BSOFF) + _j * 4096 + wave * 1024], 16, 0, 0); \
    } while (0)

    int Bbase[4];
#pragma unroll
    for (int ni = 0; ni < 4; ni++) Bbase[ni] = (wave_n + ni * 16 + l15) * 128;
    const int pB = (quad * 2) ^ (l15 & 7);    // slot of B lo-granule

    int bestk[4][4];                          // packed (value&~63 | slot) keys
#pragma unroll
    for (int mi = 0; mi < 4; mi++)
#pragma unroll
        for (int reg = 0; reg < 4; reg++) bestk[mi][reg] = 0x80000000;   // INT_MIN

    f32x4 acc[4][4];
    const f32x4 zero4 = (f32x4){0.f, 0.f, 0.f, 0.f};

// K lo half: fresh accumulate (zero C operand -> no reset movs needed)
#define COMPUTE0(BSOFF) do {                                                           \
        __builtin_amdgcn_s_setprio(1);                                                 \
        _Pragma("unroll")                                                              \
        for (int ni = 0; ni < 4; ni++) {                                               \
            const int _lo = (BSOFF) + Bbase[ni] + (pB << 4);                           \
            v4i _x = *(const v4i*)&sh[_lo];                                            \
            v4i _y = *(const v4i*)&sh[_lo ^ 16];                                       \
            v8i bv = __builtin_shufflevector(_x, _y, 0, 1, 2, 3, 4, 5, 6, 7);          \
            _Pragma("unroll")                                                          \
            for (int mi = 0; mi < 4; mi++)                                             \
                acc[mi][ni] = MFMA_FP8(areg[0][mi], bv, zero4);                        \
        }                                                                              \
        __builtin_amdgcn_s_setprio(0);                                                 \
    } while (0)

// K hi half: chain on lo half
#define COMPUTE1(BSOFF) do {                                                           \
        __builtin_amdgcn_s_setprio(1);                                                 \
        _Pragma("unroll")                                                              \
        for (int ni = 0; ni < 4; ni++) {                                               \
            const int _lo = (BSOFF) + Bbase[ni] + (pB << 4);                           \
            v4i _x = *(const v4i*)&sh[_lo];                                            \
            v4i _y = *(const v4i*)&sh[_lo ^ 16];                                       \
            v8i bv = __builtin_shufflevector(_x, _y, 0, 1, 2, 3, 4, 5, 6, 7);          \
            _Pragma("unroll")                                                          \
            for (int mi = 0; mi < 4; mi++)                                             \
                acc[mi][ni] = MFMA_FP8(areg[1][mi], bv, acc[mi][ni]);                  \
        }                                                                              \
        __builtin_amdgcn_s_setprio(0);                                                 \
    } while (0)

// fold chunk PP's acc into packed keys: v_and_or_b32 + v_max_i32 per element.
// 6-bit slot: 64 = NCHUNK*4 (p,ni) pairs; bigger slot = smaller col.
#define FOLDK(PP) do {                                                                 \
        _Pragma("unroll")                                                              \
        for (int ni = 0; ni < 4; ni++) {                                               \
            const int _slot = 63 - ((PP) * 4 + ni);                                    \
            _Pragma("unroll")                                                          \
            for (int mi = 0; mi < 4; mi++)                                             \
                _Pragma("unroll")                                                      \
                for (int reg = 0; reg < 4; reg++) {                                    \
                    int ik = (__float_as_int(acc[mi][ni][reg]) & 0xFFFFFFC0) | _slot;  \
                    bestk[mi][reg] = max(bestk[mi][reg], ik);                          \
                }                                                                      \
        }                                                                              \
    } while (0)

#define ROT() do { int _t = b0; b0 = b1; b1 = b2; b2 = _t; } while (0)

    int b0 = 0, b1 = 16384, b2 = 32768;       // ring byte offsets (uniform)

    PREFB(0, b0);                             // prologue: tiles 0,1 in flight
    PREFB(1, b1);

    // Invariant at each half-tile phase T: b0 = tile T (landed after WAITV+BAR),
    // b1 = tile T+1 (in flight), b2 = free (tile T-1, fully consumed).
#pragma unroll 1
    for (int p = 0; p < NCHUNK; ++p) {
        // ---- phase 2p: chunk p, K[0:128)
        WAITV(4); BARRIER();
        if (p < NCHUNK - 1) PREFB(2 * p + 2, b2);
        if (p > 0) FOLDK(p - 1);              // reads old acc (WAR vs COMPUTE0)
        COMPUTE0(b0);
        ROT();
        // ---- phase 2p+1: chunk p, K[128:256)
        if (p < NCHUNK - 1) { WAITV(4); } else { WAITV(0); }
        BARRIER();
        if (p < NCHUNK - 1) PREFB(2 * p + 3, b2);
        COMPUTE1(b0);
        ROT();
    }
    FOLDK(NCHUNK - 1);                        // last chunk

    // Epilogue (once per block): decode keys, 16-lane reduce, one atomic per slot
#pragma unroll
    for (int mi = 0; mi < 4; mi++) {
#pragma unroll
        for (int reg = 0; reg < 4; reg++) {
            unsigned u     = (unsigned)bestk[mi][reg];
            unsigned vbits = u & 0xFFFFFFC0u;
            int      pni   = 63 - (int)(u & 63u);
            int      col   = nbase + (pni >> 2) * BN + wave_n + ((pni & 3) << 4) + l15;
            unsigned ov    = (vbits & 0x80000000u) ? ~vbits : (vbits | 0x80000000u);
            unsigned long long key =
                ((unsigned long long)ov << 32) |
                (unsigned long long)(0xFFFFFFFFu - (unsigned)col);   // ~col: ties -> smaller col
#pragma unroll
            for (int m = 1; m < 16; m <<= 1) {
                unsigned long long o = __shfl_xor(key, m, 16);
                if (o > key) key = o;
            }
            if (l15 == mi * 4 + reg) {
                int row = blk_m + wave_m + mi * 16 + quad * 4 + reg;
                atomicMax(&amax[row], key);
            }
        }
    }
}

// ---------- logits + online logsumexp - diag + final reduce ----------
// R18 body: two independent 4-deep MFMA chains per tile.
__global__ __launch_bounds__(512) void logits_ce_kernel(const unsigned long long* __restrict__ amax,
                                                        const float* __restrict__ queue_f32,
                                                        const unsigned short* __restrict__ preds_bf,
                                                        float* __restrict__ out) {
    const int gw   = blockIdx.x;        // 0..255 (16-row group)
    const int tid  = threadIdx.x;
    const int wave = tid >> 6;          // 0..7
    const int lane = tid & 63;
    const int l15  = lane & 15;
    const int quad = lane >> 4;
    const int h    = gw >> 7;           // 0: ab, 1: ba
    const int rowbase = gw * 16;
    const unsigned short* Bbase = preds_bf + (size_t)((1 - h) * HALF) * D_K;

    __shared__ float sm[8][16], sl[8][16], sd[8][16];

    // inline gather from fp32 queue: this lane's A-row = queue[argmax(rowbase+l15)]
    unsigned idx = 0xFFFFFFFFu - (unsigned)(amax[rowbase + l15] & 0xFFFFFFFFull);
    const float* arow = queue_f32 + (size_t)idx * D_K;
    bf16x8 a[8];
#pragma unroll
    for (int kc = 0; kc < 8; kc++) {
        float4 f0 = *(const float4*)(arow + kc * 32 + quad * 8);
        float4 f1 = *(const float4*)(arow + kc * 32 + quad * 8 + 4);
        u16x8 t;
        t[0] = f2bf_rn(f0.x); t[1] = f2bf_rn(f0.y); t[2] = f2bf_rn(f0.z); t[3] = f2bf_rn(f0.w);
        t[4] = f2bf_rn(f1.x); t[5] = f2bf_rn(f1.y); t[6] = f2bf_rn(f1.z); t[7] = f2bf_rn(f1.w);
        a[kc] = *(const bf16x8*)&t;
    }

    float m_run[4], l_run[4], diag[4];
#pragma unroll
    for (int r = 0; r < 4; r++) { m_run[r] = -1e30f; l_run[r] = 0.f; diag[r] = -1e30f; }

    const int tdiag = gw & 127;
    for (int tt = 0; tt < 16; tt++) {
        const int t = wave * 16 + tt;
        f32x4 acc0 = (f32x4){0.f, 0.f, 0.f, 0.f};
        f32x4 acc1 = (f32x4){0.f, 0.f, 0.f, 0.f};
#pragma unroll
        for (int kc = 0; kc < 4; kc++) {
            bf16x8 b0 = *(const bf16x8*)&Bbase[(size_t)(t * 16 + l15) * D_K + kc * 32 + quad * 8];
            acc0 = __builtin_amdgcn_mfma_f32_16x16x32_bf16(a[kc], b0, acc0, 0, 0, 0);
            bf16x8 b1 = *(const bf16x8*)&Bbase[(size_t)(t * 16 + l15) * D_K + (kc + 4) * 32 + quad * 8];
            acc1 = __builtin_amdgcn_mfma_f32_16x16x32_bf16(a[kc + 4], b1, acc1, 0, 0, 0);
        }
        f32x4 acc = acc0 + acc1;
#pragma unroll
        for (int reg = 0; reg < 4; reg++) {
            float v = acc[reg] * 10.0f;              // 1/TEMPERATURE
            if (t == tdiag && l15 == quad * 4 + reg) diag[reg] = v;
            float nm = fmaxf(m_run[reg], v);
            l_run[reg] = l_run[reg] * __expf(m_run[reg] - nm) + __expf(v - nm);
            m_run[reg] = nm;
        }
    }
    // 16-lane merge within the wave
#pragma unroll
    for (int reg = 0; reg < 4; reg++) {
#pragma unroll
        for (int m = 1; m < 16; m <<= 1) {
            float om = __shfl_xor(m_run[reg], m, 16);
            float ol = __shfl_xor(l_run[reg], m, 16);
            float od = __shfl_xor(diag[reg], m, 16);
            float nm = fmaxf(m_run[reg], om);
            l_run[reg] = l_run[reg] * __expf(m_run[reg] - nm) + ol * __expf(om - nm);
            m_run[reg] = nm;
            diag[reg] = fmaxf(diag[reg], od);
        }
        if (l15 == 0) {
            sm[wave][quad * 4 + reg] = m_run[reg];
            sl[wave][quad * 4 + reg] = l_run[reg];
            sd[wave][quad * 4 + reg] = diag[reg];
        }
    }
    __syncthreads();
    // cross-wave merge + block-local reduce + single atomic into out
    if (tid < 16) {
        float M = -1e30f, L = 0.f, Dg = -1e30f;
#pragma unroll
        for (int w = 0; w < 8; w++) {
            float mw = sm[w][tid], lw = sl[w][tid], dw = sd[w][tid];
            float nM = fmaxf(M, mw);
            L = L * __expf(M - nM) + lw * __expf(mw - nM);
            M = nM;
            Dg = fmaxf(Dg, dw);
        }
        float rl = (M + __logf(L)) - Dg;
#pragma unroll
        for (int m = 1; m < 16; m <<= 1) rl += __shfl_xor(rl, m, 16);
        if (tid == 0) atomicAdd(out, rl * (1.0f / (float)B_ROWS));
    }
}

extern "C" void kernel_launch(void* const* d_in, const int* in_sizes, int n_in,
                              void* d_out, int out_size, void* d_ws, size_t ws_size,
                              hipStream_t stream) {
    const float* emb   = (const float*)d_in[0];
    const float* preds = (const float*)d_in[1];
    const float* queue = (const float*)d_in[2];

    char* w = (char*)d_ws;
    unsigned long long* amax  = (unsigned long long*)w;                     // 32 KB
    unsigned char*  emb8      = (unsigned char*)(w + (1u << 20));           // 1 MB
    unsigned short* preds_bf  = (unsigned short*)(w + (2u << 20));          // 2 MB
    unsigned char*  queue8    = (unsigned char*)(w + (4u << 20));           // 16 MB

    prep_kernel<<<dim3(PREP_THREADS / 256), 256, 0, stream>>>(
        emb, preds, queue, emb8, preds_bf, queue8, amax, (float*)d_out);
    sim_argmax_kernel<<<dim3((B_ROWS / BM) * (Q_ROWS / (BN * NCHUNK))), 256, 0, stream>>>(
        emb8, queue8, amax);
    logits_ce_kernel<<<dim3(B_ROWS / 16), 512, 0, stream>>>(
        amax, queue, preds_bf, (float*)d_out);
}

// Round 11
// 195.290 us; speedup vs baseline: 1.4264x; 1.0091x over previous
//
#include <hip/hip_runtime.h>
#include <hip/hip_bf16.h>
#include <stdint.h>

#define B_ROWS 4096
#define D_K    256
#define Q_ROWS 65536
#define HALF   2048

typedef __bf16 bf16x8 __attribute__((ext_vector_type(8)));
typedef float  f32x4  __attribute__((ext_vector_type(4)));
typedef int    v8i    __attribute__((ext_vector_type(8)));
typedef int    v4i    __attribute__((ext_vector_type(4)));
typedef unsigned short u16x8 __attribute__((ext_vector_type(8)));
typedef const __attribute__((address_space(1))) void* gptr1;
typedef __attribute__((address_space(3))) void* lptr3;

__device__ __forceinline__ unsigned int f32_ordered(float f) {
    unsigned int u = __float_as_uint(f);
    return (u & 0x80000000u) ? ~u : (u | 0x80000000u);
}

__device__ __forceinline__ unsigned short f2bf_rn(float f) {
    unsigned int u = __float_as_uint(f);
    u += 0x7FFFu + ((u >> 16) & 1u);
    return (unsigned short)(u >> 16);
}

// ---------- fused prep: emb/queue -> fp8 e4m3, preds -> bf16, zero amax/out ----------
// R18 body: 16 elements/thread, int4 stores for fp8, ushort8 stores for bf16.
#define EMB4  (B_ROWS * D_K / 4)          // 262144 granules
#define PRED4 (B_ROWS * D_K / 4)          // 262144
#define QUE4  (Q_ROWS * D_K / 4)          // 4194304
#define PREP_THREADS ((EMB4 + PRED4 + QUE4) / 4)   // 1179648
__global__ __launch_bounds__(256) void prep_kernel(const float* __restrict__ emb,
                                                   const float* __restrict__ preds,
                                                   const float* __restrict__ queue,
                                                   unsigned char* __restrict__ emb8,
                                                   unsigned short* __restrict__ preds_bf,
                                                   unsigned char* __restrict__ queue8,
                                                   unsigned long long* __restrict__ amax,
                                                   float* __restrict__ out) {
    const int t  = blockIdx.x * 256 + threadIdx.x;
    const int g0 = t * 4;                 // first granule (4 floats each)
    if (g0 < EMB4) {
        const float4* src = (const float4*)emb + g0;
        int4 o;
        { float4 v = src[0]; int u = __builtin_amdgcn_cvt_pk_fp8_f32(v.x, v.y, 0, false);
          o.x = __builtin_amdgcn_cvt_pk_fp8_f32(v.z, v.w, u, true); }
        { float4 v = src[1]; int u = __builtin_amdgcn_cvt_pk_fp8_f32(v.x, v.y, 0, false);
          o.y = __builtin_amdgcn_cvt_pk_fp8_f32(v.z, v.w, u, true); }
        { float4 v = src[2]; int u = __builtin_amdgcn_cvt_pk_fp8_f32(v.x, v.y, 0, false);
          o.z = __builtin_amdgcn_cvt_pk_fp8_f32(v.z, v.w, u, true); }
        { float4 v = src[3]; int u = __builtin_amdgcn_cvt_pk_fp8_f32(v.x, v.y, 0, false);
          o.w = __builtin_amdgcn_cvt_pk_fp8_f32(v.z, v.w, u, true); }
        ((int4*)emb8)[t] = o;
    } else if (g0 < EMB4 + PRED4) {
        const int off = g0 - EMB4;        // granule offset, divisible by 4
        const float4* src = (const float4*)preds + off;
#pragma unroll
        for (int h = 0; h < 2; h++) {
            float4 v0 = src[2 * h], v1 = src[2 * h + 1];
            u16x8 o;
            o[0] = f2bf_rn(v0.x); o[1] = f2bf_rn(v0.y); o[2] = f2bf_rn(v0.z); o[3] = f2bf_rn(v0.w);
            o[4] = f2bf_rn(v1.x); o[5] = f2bf_rn(v1.y); o[6] = f2bf_rn(v1.z); o[7] = f2bf_rn(v1.w);
            ((u16x8*)preds_bf)[(off >> 1) + h] = o;
        }
    } else {
        const int off = g0 - EMB4 - PRED4;
        const float4* src = (const float4*)queue + off;
        int4 o;
        { float4 v = src[0]; int u = __builtin_amdgcn_cvt_pk_fp8_f32(v.x, v.y, 0, false);
          o.x = __builtin_amdgcn_cvt_pk_fp8_f32(v.z, v.w, u, true); }
        { float4 v = src[1]; int u = __builtin_amdgcn_cvt_pk_fp8_f32(v.x, v.y, 0, false);
          o.y = __builtin_amdgcn_cvt_pk_fp8_f32(v.z, v.w, u, true); }
        { float4 v = src[2]; int u = __builtin_amdgcn_cvt_pk_fp8_f32(v.x, v.y, 0, false);
          o.z = __builtin_amdgcn_cvt_pk_fp8_f32(v.z, v.w, u, true); }
        { float4 v = src[3]; int u = __builtin_amdgcn_cvt_pk_fp8_f32(v.x, v.y, 0, false);
          o.w = __builtin_amdgcn_cvt_pk_fp8_f32(v.z, v.w, u, true); }
        ((int4*)queue8)[off >> 2] = o;
    }
    if (t < B_ROWS) amax[t] = 0ull;   // ordered-float 0 == below every real value
    if (t == 0) out[0] = 0.f;
}

// ---------- fused sim GEMM + row argmax, MX-fp8 (scale=1.0) ----------
// R21 = R20 with NCHUNK 16 -> 32: grid 512 = 2 blocks/CU EXACTLY, one single
// co-resident round (no sequential round boundary, no second prologue/
// epilogue, no inter-round tail). R20 proved the round-elimination lever:
// 4->2 rounds saved 13.2us (~6.6us/round). This is the last step.
// Packed-key slot widens to 7 bits (128 (p,ni) pairs); masked tie-window
// 128 ulp (~1e-3) still >=2 orders below the top1-top2 gap scale and below
// the fp8 quantization noise argmax already survives (absmax 0, six runs).
// PINNED by experiment: launch_bounds(256,2) [R13/R15]; 16x16x128 [R17];
// LDS-staged B [R19]; ring + counted vmcnt(4); packed-key deferred fold.
#define BM 128
#define BN 128
#define NCHUNK 32
#define MFMA_FP8(av, bv, c) \
    __builtin_amdgcn_mfma_scale_f32_16x16x128_f8f6f4((av), (bv), (c), 0, 0, 0, 0x7F7F7F7F, 0, 0x7F7F7F7F)

#define WAITV(N) asm volatile("s_waitcnt vmcnt(" #N ")" ::: "memory")
#define BARRIER() do { __builtin_amdgcn_s_barrier(); \
                       asm volatile("" ::: "memory"); \
                       __builtin_amdgcn_sched_barrier(0); } while (0)

__global__ __launch_bounds__(256, 2) void sim_argmax_kernel(const unsigned char* __restrict__ A8,
                                                            const unsigned char* __restrict__ B8,
                                                            unsigned long long* __restrict__ amax) {
    __shared__ unsigned char sh[49152];   // phase 1: A tile (32 KB); phase 2: B ring (3 x 16 KB)

    const int tid  = threadIdx.x;
    const int wave = tid >> 6;          // 0..3
    const int lane = tid & 63;
    const int l15  = lane & 15;
    const int quad = lane >> 4;

    // XCD-aware swizzle: block i -> XCD i%8. 512 blocks = 64/XCD = 2/CU exact.
    const int bid  = blockIdx.x;
    const int xcd  = bid & 7;
    const int j    = bid >> 3;
    const int blk_m = (j & 31) * BM;
    const int ngrp  = (j >> 5) * 8 + xcd;         // 0..15
    const int nbase = ngrp * (BN * NCHUNK);

    const int wave_m = (wave >> 1) * 64;
    const int wave_n = (wave & 1) * 64;

    // ---- phase 1: stage A (32 KB) into sh, swizzled: LDS byte j*4096 + tid*16
    // holds row r = j*16 + (tid>>4), slot tid&15; global granule g = slot ^ (r&15).
    {
        const unsigned char* gA = A8 + (size_t)(blk_m + (tid >> 4)) * D_K
                                     + (((tid & 15) ^ ((tid >> 4) & 15)) << 4);
#pragma unroll
        for (int jj = 0; jj < 8; jj++)
            __builtin_amdgcn_global_load_lds((gptr1)(gA + jj * 4096),
                                             (lptr3)&sh[jj * 4096 + wave * 1024], 16, 0, 0);
    }
    __syncthreads();   // A resident in LDS

    // read A fragments into registers: areg[kt][mi], 8 x v8i = 64 VGPRs
    const int pA = (quad * 2) ^ l15;          // slot of A lo-granule for kt=0
    v8i areg[2][4];
#pragma unroll
    for (int kt = 0; kt < 2; kt++) {
#pragma unroll
        for (int mi = 0; mi < 4; mi++) {
            const int _lo = (wave_m + mi * 16 + l15) * 256 + ((pA ^ (kt << 3)) << 4);
            v4i _x = *(const v4i*)&sh[_lo];
            v4i _y = *(const v4i*)&sh[_lo ^ 16];
            areg[kt][mi] = __builtin_shufflevector(_x, _y, 0, 1, 2, 3, 4, 5, 6, 7);
        }
    }
    __syncthreads();   // all lanes done reading A; sh becomes the B ring

    // ---- B staging base: issue j covers rows j*32 + (tid>>3), slot tid&7,
    // global granule g = slot ^ (r&7). Tile T: +(T>>1)*32768 + (T&1)*128 bytes.
    const unsigned char* gB = B8 + (size_t)(nbase + (tid >> 3)) * D_K
                                 + (((tid & 7) ^ ((tid >> 3) & 7)) << 4);

#define PREFB(T, BSOFF) do {                                                           \
        const int _off = ((T) >> 1) * (32 * D_K * 4) + ((T) & 1) * 128;                \
        _Pragma("unroll")                                                              \
        for (int _j = 0; _j < 4; _j++)                                                 \
            __builtin_amdgcn_global_load_lds((gptr1)(gB + _j * 8192 + _off),           \
                                             (lptr3)&sh[(BSOFF) + _j * 4096 + wave * 1024], 16, 0, 0); \
    } while (0)

    int Bbase[4];
#pragma unroll
    for (int ni = 0; ni < 4; ni++) Bbase[ni] = (wave_n + ni * 16 + l15) * 128;
    const int pB = (quad * 2) ^ (l15 & 7);    // slot of B lo-granule

    int bestk[4][4];                          // packed (value&~127 | slot) keys
#pragma unroll
    for (int mi = 0; mi < 4; mi++)
#pragma unroll
        for (int reg = 0; reg < 4; reg++) bestk[mi][reg] = 0x80000000;   // INT_MIN

    f32x4 acc[4][4];
    const f32x4 zero4 = (f32x4){0.f, 0.f, 0.f, 0.f};

// K lo half: fresh accumulate (zero C operand -> no reset movs needed)
#define COMPUTE0(BSOFF) do {                                                           \
        __builtin_amdgcn_s_setprio(1);                                                 \
        _Pragma("unroll")                                                              \
        for (int ni = 0; ni < 4; ni++) {                                               \
            const int _lo = (BSOFF) + Bbase[ni] + (pB << 4);                           \
            v4i _x = *(const v4i*)&sh[_lo];                                            \
            v4i _y = *(const v4i*)&sh[_lo ^ 16];                                       \
            v8i bv = __builtin_shufflevector(_x, _y, 0, 1, 2, 3, 4, 5, 6, 7);          \
            _Pragma("unroll")                                                          \
            for (int mi = 0; mi < 4; mi++)                                             \
                acc[mi][ni] = MFMA_FP8(areg[0][mi], bv, zero4);                        \
        }                                                                              \
        __builtin_amdgcn_s_setprio(0);                                                 \
    } while (0)

// K hi half: chain on lo half
#define COMPUTE1(BSOFF) do {                                                           \
        __builtin_amdgcn_s_setprio(1);                                                 \
        _Pragma("unroll")                                                              \
        for (int ni = 0; ni < 4; ni++) {                                               \
            const int _lo = (BSOFF) + Bbase[ni] + (pB << 4);                           \
            v4i _x = *(const v4i*)&sh[_lo];                                            \
            v4i _y = *(const v4i*)&sh[_lo ^ 16];                                       \
            v8i bv = __builtin_shufflevector(_x, _y, 0, 1, 2, 3, 4, 5, 6, 7);          \
            _Pragma("unroll")                                                          \
            for (int mi = 0; mi < 4; mi++)                                             \
                acc[mi][ni] = MFMA_FP8(areg[1][mi], bv, acc[mi][ni]);                  \
        }                                                                              \
        __builtin_amdgcn_s_setprio(0);                                                 \
    } while (0)

// fold chunk PP's acc into packed keys: v_and_or_b32 + v_max_i32 per element.
// 7-bit slot: 128 = NCHUNK*4 (p,ni) pairs; bigger slot = smaller col.
#define FOLDK(PP) do {                                                                 \
        _Pragma("unroll")                                                              \
        for (int ni = 0; ni < 4; ni++) {                                               \
            const int _slot = 127 - ((PP) * 4 + ni);                                   \
            _Pragma("unroll")                                                          \
            for (int mi = 0; mi < 4; mi++)                                             \
                _Pragma("unroll")                                                      \
                for (int reg = 0; reg < 4; reg++) {                                    \
                    int ik = (__float_as_int(acc[mi][ni][reg]) & 0xFFFFFF80) | _slot;  \
                    bestk[mi][reg] = max(bestk[mi][reg], ik);                          \
                }                                                                      \
        }                                                                              \
    } while (0)

#define ROT() do { int _t = b0; b0 = b1; b1 = b2; b2 = _t; } while (0)

    int b0 = 0, b1 = 16384, b2 = 32768;       // ring byte offsets (uniform)

    PREFB(0, b0);                             // prologue: tiles 0,1 in flight
    PREFB(1, b1);

    // Invariant at each half-tile phase T: b0 = tile T (landed after WAITV+BAR),
    // b1 = tile T+1 (in flight), b2 = free (tile T-1, fully consumed).
#pragma unroll 1
    for (int p = 0; p < NCHUNK; ++p) {
        // ---- phase 2p: chunk p, K[0:128)
        WAITV(4); BARRIER();
        if (p < NCHUNK - 1) PREFB(2 * p + 2, b2);
        if (p > 0) FOLDK(p - 1);              // reads old acc (WAR vs COMPUTE0)
        COMPUTE0(b0);
        ROT();
        // ---- phase 2p+1: chunk p, K[128:256)
        if (p < NCHUNK - 1) { WAITV(4); } else { WAITV(0); }
        BARRIER();
        if (p < NCHUNK - 1) PREFB(2 * p + 3, b2);
        COMPUTE1(b0);
        ROT();
    }
    FOLDK(NCHUNK - 1);                        // last chunk

    // Epilogue (once per block): decode keys, 16-lane reduce, one atomic per slot
#pragma unroll
    for (int mi = 0; mi < 4; mi++) {
#pragma unroll
        for (int reg = 0; reg < 4; reg++) {
            unsigned u     = (unsigned)bestk[mi][reg];
            unsigned vbits = u & 0xFFFFFF80u;
            int      pni   = 127 - (int)(u & 127u);
            int      col   = nbase + (pni >> 2) * BN + wave_n + ((pni & 3) << 4) + l15;
            unsigned ov    = (vbits & 0x80000000u) ? ~vbits : (vbits | 0x80000000u);
            unsigned long long key =
                ((unsigned long long)ov << 32) |
                (unsigned long long)(0xFFFFFFFFu - (unsigned)col);   // ~col: ties -> smaller col
#pragma unroll
            for (int m = 1; m < 16; m <<= 1) {
                unsigned long long o = __shfl_xor(key, m, 16);
                if (o > key) key = o;
            }
            if (l15 == mi * 4 + reg) {
                int row = blk_m + wave_m + mi * 16 + quad * 4 + reg;
                atomicMax(&amax[row], key);
            }
        }
    }
}

// ---------- logits + online logsumexp - diag + final reduce ----------
// R18 body: two independent 4-deep MFMA chains per tile.
__global__ __launch_bounds__(512) void logits_ce_kernel(const unsigned long long* __restrict__ amax,
                                                        const float* __restrict__ queue_f32,
                                                        const unsigned short* __restrict__ preds_bf,
                                                        float* __restrict__ out) {
    const int gw   = blockIdx.x;        // 0..255 (16-row group)
    const int tid  = threadIdx.x;
    const int wave = tid >> 6;          // 0..7
    const int lane = tid & 63;
    const int l15  = lane & 15;
    const int quad = lane >> 4;
    const int h    = gw >> 7;           // 0: ab, 1: ba
    const int rowbase = gw * 16;
    const unsigned short* Bbase = preds_bf + (size_t)((1 - h) * HALF) * D_K;

    __shared__ float sm[8][16], sl[8][16], sd[8][16];

    // inline gather from fp32 queue: this lane's A-row = queue[argmax(rowbase+l15)]
    unsigned idx = 0xFFFFFFFFu - (unsigned)(amax[rowbase + l15] & 0xFFFFFFFFull);
    const float* arow = queue_f32 + (size_t)idx * D_K;
    bf16x8 a[8];
#pragma unroll
    for (int kc = 0; kc < 8; kc++) {
        float4 f0 = *(const float4*)(arow + kc * 32 + quad * 8);
        float4 f1 = *(const float4*)(arow + kc * 32 + quad * 8 + 4);
        u16x8 t;
        t[0] = f2bf_rn(f0.x); t[1] = f2bf_rn(f0.y); t[2] = f2bf_rn(f0.z); t[3] = f2bf_rn(f0.w);
        t[4] = f2bf_rn(f1.x); t[5] = f2bf_rn(f1.y); t[6] = f2bf_rn(f1.z); t[7] = f2bf_rn(f1.w);
        a[kc] = *(const bf16x8*)&t;
    }

    float m_run[4], l_run[4], diag[4];
#pragma unroll
    for (int r = 0; r < 4; r++) { m_run[r] = -1e30f; l_run[r] = 0.f; diag[r] = -1e30f; }

    const int tdiag = gw & 127;
    for (int tt = 0; tt < 16; tt++) {
        const int t = wave * 16 + tt;
        f32x4 acc0 = (f32x4){0.f, 0.f, 0.f, 0.f};
        f32x4 acc1 = (f32x4){0.f, 0.f, 0.f, 0.f};
#pragma unroll
        for (int kc = 0; kc < 4; kc++) {
            bf16x8 b0 = *(const bf16x8*)&Bbase[(size_t)(t * 16 + l15) * D_K + kc * 32 + quad * 8];
            acc0 = __builtin_amdgcn_mfma_f32_16x16x32_bf16(a[kc], b0, acc0, 0, 0, 0);
            bf16x8 b1 = *(const bf16x8*)&Bbase[(size_t)(t * 16 + l15) * D_K + (kc + 4) * 32 + quad * 8];
            acc1 = __builtin_amdgcn_mfma_f32_16x16x32_bf16(a[kc + 4], b1, acc1, 0, 0, 0);
        }
        f32x4 acc = acc0 + acc1;
#pragma unroll
        for (int reg = 0; reg < 4; reg++) {
            float v = acc[reg] * 10.0f;              // 1/TEMPERATURE
            if (t == tdiag && l15 == quad * 4 + reg) diag[reg] = v;
            float nm = fmaxf(m_run[reg], v);
            l_run[reg] = l_run[reg] * __expf(m_run[reg] - nm) + __expf(v - nm);
            m_run[reg] = nm;
        }
    }
    // 16-lane merge within the wave
#pragma unroll
    for (int reg = 0; reg < 4; reg++) {
#pragma unroll
        for (int m = 1; m < 16; m <<= 1) {
            float om = __shfl_xor(m_run[reg], m, 16);
            float ol = __shfl_xor(l_run[reg], m, 16);
            float od = __shfl_xor(diag[reg], m, 16);
            float nm = fmaxf(m_run[reg], om);
            l_run[reg] = l_run[reg] * __expf(m_run[reg] - nm) + ol * __expf(om - nm);
            m_run[reg] = nm;
            diag[reg] = fmaxf(diag[reg], od);
        }
        if (l15 == 0) {
            sm[wave][quad * 4 + reg] = m_run[reg];
            sl[wave][quad * 4 + reg] = l_run[reg];
            sd[wave][quad * 4 + reg] = diag[reg];
        }
    }
    __syncthreads();
    // cross-wave merge + block-local reduce + single atomic into out
    if (tid < 16) {
        float M = -1e30f, L = 0.f, Dg = -1e30f;
#pragma unroll
        for (int w = 0; w < 8; w++) {
            float mw = sm[w][tid], lw = sl[w][tid], dw = sd[w][tid];
            float nM = fmaxf(M, mw);
            L = L * __expf(M - nM) + lw * __expf(mw - nM);
            M = nM;
            Dg = fmaxf(Dg, dw);
        }
        float rl = (M + __logf(L)) - Dg;
#pragma unroll
        for (int m = 1; m < 16; m <<= 1) rl += __shfl_xor(rl, m, 16);
        if (tid == 0) atomicAdd(out, rl * (1.0f / (float)B_ROWS));
    }
}

extern "C" void kernel_launch(void* const* d_in, const int* in_sizes, int n_in,
                              void* d_out, int out_size, void* d_ws, size_t ws_size,
                              hipStream_t stream) {
    const float* emb   = (const float*)d_in[0];
    const float* preds = (const float*)d_in[1];
    const float* queue = (const float*)d_in[2];

    char* w = (char*)d_ws;
    unsigned long long* amax  = (unsigned long long*)w;                     // 32 KB
    unsigned char*  emb8      = (unsigned char*)(w + (1u << 20));           // 1 MB
    unsigned short* preds_bf  = (unsigned short*)(w + (2u << 20));          // 2 MB
    unsigned char*  queue8    = (unsigned char*)(w + (4u << 20));           // 16 MB

    prep_kernel<<<dim3(PREP_THREADS / 256), 256, 0, stream>>>(
        emb, preds, queue, emb8, preds_bf, queue8, amax, (float*)d_out);
    sim_argmax_kernel<<<dim3((B_ROWS / BM) * (Q_ROWS / (BN * NCHUNK))), 256, 0, stream>>>(
        emb8, queue8, amax);
    logits_ce_kernel<<<dim3(B_ROWS / 16), 512, 0, stream>>>(
        amax, queue, preds_bf, (float*)d_out);
}

// Round 12
// 193.403 us; speedup vs baseline: 1.4403x; 1.0098x over previous
//
#include <hip/hip_runtime.h>
#include <hip/hip_bf16.h>
#include <stdint.h>

#define B_ROWS 4096
#define D_K    256
#define Q_ROWS 65536
#define HALF   2048

typedef __bf16 bf16x8 __attribute__((ext_vector_type(8)));
typedef float  f32x4  __attribute__((ext_vector_type(4)));
typedef int    v8i    __attribute__((ext_vector_type(8)));
typedef int    v4i    __attribute__((ext_vector_type(4)));
typedef unsigned short u16x8 __attribute__((ext_vector_type(8)));
typedef const __attribute__((address_space(1))) void* gptr1;
typedef __attribute__((address_space(3))) void* lptr3;

__device__ __forceinline__ unsigned int f32_ordered(float f) {
    unsigned int u = __float_as_uint(f);
    return (u & 0x80000000u) ? ~u : (u | 0x80000000u);
}

__device__ __forceinline__ unsigned short f2bf_rn(float f) {
    unsigned int u = __float_as_uint(f);
    u += 0x7FFFu + ((u >> 16) & 1u);
    return (unsigned short)(u >> 16);
}

// ---------- fused prep: emb/queue -> fp8 e4m3, preds -> bf16, zero amax/out ----------
// R18 body: 16 elements/thread, int4 stores for fp8, ushort8 stores for bf16.
#define EMB4  (B_ROWS * D_K / 4)          // 262144 granules
#define PRED4 (B_ROWS * D_K / 4)          // 262144
#define QUE4  (Q_ROWS * D_K / 4)          // 4194304
#define PREP_THREADS ((EMB4 + PRED4 + QUE4) / 4)   // 1179648
__global__ __launch_bounds__(256) void prep_kernel(const float* __restrict__ emb,
                                                   const float* __restrict__ preds,
                                                   const float* __restrict__ queue,
                                                   unsigned char* __restrict__ emb8,
                                                   unsigned short* __restrict__ preds_bf,
                                                   unsigned char* __restrict__ queue8,
                                                   unsigned long long* __restrict__ amax,
                                                   float* __restrict__ out) {
    const int t  = blockIdx.x * 256 + threadIdx.x;
    const int g0 = t * 4;                 // first granule (4 floats each)
    if (g0 < EMB4) {
        const float4* src = (const float4*)emb + g0;
        int4 o;
        { float4 v = src[0]; int u = __builtin_amdgcn_cvt_pk_fp8_f32(v.x, v.y, 0, false);
          o.x = __builtin_amdgcn_cvt_pk_fp8_f32(v.z, v.w, u, true); }
        { float4 v = src[1]; int u = __builtin_amdgcn_cvt_pk_fp8_f32(v.x, v.y, 0, false);
          o.y = __builtin_amdgcn_cvt_pk_fp8_f32(v.z, v.w, u, true); }
        { float4 v = src[2]; int u = __builtin_amdgcn_cvt_pk_fp8_f32(v.x, v.y, 0, false);
          o.z = __builtin_amdgcn_cvt_pk_fp8_f32(v.z, v.w, u, true); }
        { float4 v = src[3]; int u = __builtin_amdgcn_cvt_pk_fp8_f32(v.x, v.y, 0, false);
          o.w = __builtin_amdgcn_cvt_pk_fp8_f32(v.z, v.w, u, true); }
        ((int4*)emb8)[t] = o;
    } else if (g0 < EMB4 + PRED4) {
        const int off = g0 - EMB4;        // granule offset, divisible by 4
        const float4* src = (const float4*)preds + off;
#pragma unroll
        for (int h = 0; h < 2; h++) {
            float4 v0 = src[2 * h], v1 = src[2 * h + 1];
            u16x8 o;
            o[0] = f2bf_rn(v0.x); o[1] = f2bf_rn(v0.y); o[2] = f2bf_rn(v0.z); o[3] = f2bf_rn(v0.w);
            o[4] = f2bf_rn(v1.x); o[5] = f2bf_rn(v1.y); o[6] = f2bf_rn(v1.z); o[7] = f2bf_rn(v1.w);
            ((u16x8*)preds_bf)[(off >> 1) + h] = o;
        }
    } else {
        const int off = g0 - EMB4 - PRED4;
        const float4* src = (const float4*)queue + off;
        int4 o;
        { float4 v = src[0]; int u = __builtin_amdgcn_cvt_pk_fp8_f32(v.x, v.y, 0, false);
          o.x = __builtin_amdgcn_cvt_pk_fp8_f32(v.z, v.w, u, true); }
        { float4 v = src[1]; int u = __builtin_amdgcn_cvt_pk_fp8_f32(v.x, v.y, 0, false);
          o.y = __builtin_amdgcn_cvt_pk_fp8_f32(v.z, v.w, u, true); }
        { float4 v = src[2]; int u = __builtin_amdgcn_cvt_pk_fp8_f32(v.x, v.y, 0, false);
          o.z = __builtin_amdgcn_cvt_pk_fp8_f32(v.z, v.w, u, true); }
        { float4 v = src[3]; int u = __builtin_amdgcn_cvt_pk_fp8_f32(v.x, v.y, 0, false);
          o.w = __builtin_amdgcn_cvt_pk_fp8_f32(v.z, v.w, u, true); }
        ((int4*)queue8)[off >> 2] = o;
    }
    if (t < B_ROWS) amax[t] = 0ull;   // ordered-float 0 == below every real value
    if (t == 0) out[0] = 0.f;
}

// ---------- fused sim GEMM + row argmax, MX-fp8 (scale=1.0) ----------
// R22 = R21 with the 3x16KB half-chunk ring replaced by a 4x16KB full-chunk
// ring: ONE barrier per chunk (32 total, was 64). R21 accounting: wall
// 2440cy/phase, matrix 1104, LDS 1100 -> residual ~1300cy/phase is barrier
// lockstep + dependency serialization, paid 64x. Merged phase = 16 ds_reads
// + 32 MFMAs + fold + 8 prefetch issues: double scheduling window, half the
// lockstep points. Prefetch for chunk p+1 issues right after chunk p's
// barrier (into chunk p-1's buffers, freed by that barrier) and is consumed
// a full ~4900cy later -> WAITV(0) is effectively pre-drained (counted vmcnt
// was null anyway, R14). Buffer addr = (p&1)*32768, pure SALU.
// LDS 64KB/block -> 128KB/CU <= 160 OK, still 2 blocks/CU.
// PINNED: launch_bounds(256,2) [R13/R15]; 16x16x128 [R17]; LDS-staged B
// [R19]; NCHUNK=32 single-round [R20/R21]; packed-key deferred fold.
#define BM 128
#define BN 128
#define NCHUNK 32
#define MFMA_FP8(av, bv, c) \
    __builtin_amdgcn_mfma_scale_f32_16x16x128_f8f6f4((av), (bv), (c), 0, 0, 0, 0x7F7F7F7F, 0, 0x7F7F7F7F)

#define WAITV(N) asm volatile("s_waitcnt vmcnt(" #N ")" ::: "memory")
#define BARRIER() do { __builtin_amdgcn_s_barrier(); \
                       asm volatile("" ::: "memory"); \
                       __builtin_amdgcn_sched_barrier(0); } while (0)

__global__ __launch_bounds__(256, 2) void sim_argmax_kernel(const unsigned char* __restrict__ A8,
                                                            const unsigned char* __restrict__ B8,
                                                            unsigned long long* __restrict__ amax) {
    __shared__ unsigned char sh[65536];   // phase 1: A tile (32 KB); phase 2: B ring (4 x 16 KB)

    const int tid  = threadIdx.x;
    const int wave = tid >> 6;          // 0..3
    const int lane = tid & 63;
    const int l15  = lane & 15;
    const int quad = lane >> 4;

    // XCD-aware swizzle: block i -> XCD i%8. 512 blocks = 64/XCD = 2/CU exact.
    const int bid  = blockIdx.x;
    const int xcd  = bid & 7;
    const int j    = bid >> 3;
    const int blk_m = (j & 31) * BM;
    const int ngrp  = (j >> 5) * 8 + xcd;         // 0..15
    const int nbase = ngrp * (BN * NCHUNK);

    const int wave_m = (wave >> 1) * 64;
    const int wave_n = (wave & 1) * 64;

    // ---- phase 1: stage A (32 KB) into sh, swizzled: LDS byte j*4096 + tid*16
    // holds row r = j*16 + (tid>>4), slot tid&15; global granule g = slot ^ (r&15).
    {
        const unsigned char* gA = A8 + (size_t)(blk_m + (tid >> 4)) * D_K
                                     + (((tid & 15) ^ ((tid >> 4) & 15)) << 4);
#pragma unroll
        for (int jj = 0; jj < 8; jj++)
            __builtin_amdgcn_global_load_lds((gptr1)(gA + jj * 4096),
                                             (lptr3)&sh[jj * 4096 + wave * 1024], 16, 0, 0);
    }
    __syncthreads();   // A resident in LDS

    // read A fragments into registers: areg[kt][mi], 8 x v8i = 64 VGPRs
    const int pA = (quad * 2) ^ l15;          // slot of A lo-granule for kt=0
    v8i areg[2][4];
#pragma unroll
    for (int kt = 0; kt < 2; kt++) {
#pragma unroll
        for (int mi = 0; mi < 4; mi++) {
            const int _lo = (wave_m + mi * 16 + l15) * 256 + ((pA ^ (kt << 3)) << 4);
            v4i _x = *(const v4i*)&sh[_lo];
            v4i _y = *(const v4i*)&sh[_lo ^ 16];
            areg[kt][mi] = __builtin_shufflevector(_x, _y, 0, 1, 2, 3, 4, 5, 6, 7);
        }
    }
    __syncthreads();   // all lanes done reading A; sh becomes the B ring

    // ---- B staging base: issue j covers rows j*32 + (tid>>3), slot tid&7,
    // global granule g = slot ^ (r&7). Tile T: +(T>>1)*32768 + (T&1)*128 bytes.
    const unsigned char* gB = B8 + (size_t)(nbase + (tid >> 3)) * D_K
                                 + (((tid & 7) ^ ((tid >> 3) & 7)) << 4);

#define PREFB(T, BSOFF) do {                                                           \
        const int _off = ((T) >> 1) * (32 * D_K * 4) + ((T) & 1) * 128;                \
        _Pragma("unroll")                                                              \
        for (int _j = 0; _j < 4; _j++)                                                 \
            __builtin_amdgcn_global_load_lds((gptr1)(gB + _j * 8192 + _off),           \
                                             (lptr3)&sh[(BSOFF) + _j * 4096 + wave * 1024], 16, 0, 0); \
    } while (0)

    int Bbase[4];
#pragma unroll
    for (int ni = 0; ni < 4; ni++) Bbase[ni] = (wave_n + ni * 16 + l15) * 128;
    const int pB = (quad * 2) ^ (l15 & 7);    // slot of B lo-granule

    int bestk[4][4];                          // packed (value&~127 | slot) keys
#pragma unroll
    for (int mi = 0; mi < 4; mi++)
#pragma unroll
        for (int reg = 0; reg < 4; reg++) bestk[mi][reg] = 0x80000000;   // INT_MIN

    f32x4 acc[4][4];
    const f32x4 zero4 = (f32x4){0.f, 0.f, 0.f, 0.f};

// K lo half: fresh accumulate (zero C operand -> no reset movs needed)
#define COMPUTE0(BSOFF) do {                                                           \
        __builtin_amdgcn_s_setprio(1);                                                 \
        _Pragma("unroll")                                                              \
        for (int ni = 0; ni < 4; ni++) {                                               \
            const int _lo = (BSOFF) + Bbase[ni] + (pB << 4);                           \
            v4i _x = *(const v4i*)&sh[_lo];                                            \
            v4i _y = *(const v4i*)&sh[_lo ^ 16];                                       \
            v8i bv = __builtin_shufflevector(_x, _y, 0, 1, 2, 3, 4, 5, 6, 7);          \
            _Pragma("unroll")                                                          \
            for (int mi = 0; mi < 4; mi++)                                             \
                acc[mi][ni] = MFMA_FP8(areg[0][mi], bv, zero4);                        \
        }                                                                              \
        __builtin_amdgcn_s_setprio(0);                                                 \
    } while (0)

// K hi half: chain on lo half
#define COMPUTE1(BSOFF) do {                                                           \
        __builtin_amdgcn_s_setprio(1);                                                 \
        _Pragma("unroll")                                                              \
        for (int ni = 0; ni < 4; ni++) {                                               \
            const int _lo = (BSOFF) + Bbase[ni] + (pB << 4);                           \
            v4i _x = *(const v4i*)&sh[_lo];                                            \
            v4i _y = *(const v4i*)&sh[_lo ^ 16];                                       \
            v8i bv = __builtin_shufflevector(_x, _y, 0, 1, 2, 3, 4, 5, 6, 7);          \
            _Pragma("unroll")                                                          \
            for (int mi = 0; mi < 4; mi++)                                             \
                acc[mi][ni] = MFMA_FP8(areg[1][mi], bv, acc[mi][ni]);                  \
        }                                                                              \
        __builtin_amdgcn_s_setprio(0);                                                 \
    } while (0)

// fold chunk PP's acc into packed keys: v_and_or_b32 + v_max_i32 per element.
// 7-bit slot: 128 = NCHUNK*4 (p,ni) pairs; bigger slot = smaller col.
#define FOLDK(PP) do {                                                                 \
        _Pragma("unroll")                                                              \
        for (int ni = 0; ni < 4; ni++) {                                               \
            const int _slot = 127 - ((PP) * 4 + ni);                                   \
            _Pragma("unroll")                                                          \
            for (int mi = 0; mi < 4; mi++)                                             \
                _Pragma("unroll")                                                      \
                for (int reg = 0; reg < 4; reg++) {                                    \
                    int ik = (__float_as_int(acc[mi][ni][reg]) & 0xFFFFFF80) | _slot;  \
                    bestk[mi][reg] = max(bestk[mi][reg], ik);                          \
                }                                                                      \
        }                                                                              \
    } while (0)

    // Full-chunk ring: tile T lives at buffer (T&3)*16384. Chunk p occupies
    // bufs {(p&1)*32768, +16384}; prefetch for chunk p+1 goes to the other pair.
    PREFB(0, 0);                              // prologue: chunk 0 in flight
    PREFB(1, 16384);

    // Invariant at chunk p top: chunk p's 8 loads outstanding (issued one full
    // phase ago), chunk p-1's bufs freed by the barrier we're about to cross.
#pragma unroll 1
    for (int p = 0; p < NCHUNK; ++p) {
        const int bA = (p & 1) * 32768;       // chunk p tiles
        const int bO = bA ^ 32768;            // chunk p+1 tiles (freed pair)
        WAITV(0);                             // chunk p landed (issued ~4900cy ago)
        BARRIER();                            // everyone past chunk p-1 reads
        if (p < NCHUNK - 1) { PREFB(2 * p + 2, bO); PREFB(2 * p + 3, bO + 16384); }
        if (p > 0) FOLDK(p - 1);              // reads old acc (WAR vs COMPUTE0)
        COMPUTE0(bA);                         // chunk p, K[0:128)
        COMPUTE1(bA + 16384);                 // chunk p, K[128:256)
    }
    FOLDK(NCHUNK - 1);                        // last chunk

    // Epilogue (once per block): decode keys, 16-lane reduce, one atomic per slot
#pragma unroll
    for (int mi = 0; mi < 4; mi++) {
#pragma unroll
        for (int reg = 0; reg < 4; reg++) {
            unsigned u     = (unsigned)bestk[mi][reg];
            unsigned vbits = u & 0xFFFFFF80u;
            int      pni   = 127 - (int)(u & 127u);
            int      col   = nbase + (pni >> 2) * BN + wave_n + ((pni & 3) << 4) + l15;
            unsigned ov    = (vbits & 0x80000000u) ? ~vbits : (vbits | 0x80000000u);
            unsigned long long key =
                ((unsigned long long)ov << 32) |
                (unsigned long long)(0xFFFFFFFFu - (unsigned)col);   // ~col: ties -> smaller col
#pragma unroll
            for (int m = 1; m < 16; m <<= 1) {
                unsigned long long o = __shfl_xor(key, m, 16);
                if (o > key) key = o;
            }
            if (l15 == mi * 4 + reg) {
                int row = blk_m + wave_m + mi * 16 + quad * 4 + reg;
                atomicMax(&amax[row], key);
            }
        }
    }
}

// ---------- logits + online logsumexp - diag + final reduce ----------
// R18 body: two independent 4-deep MFMA chains per tile.
__global__ __launch_bounds__(512) void logits_ce_kernel(const unsigned long long* __restrict__ amax,
                                                        const float* __restrict__ queue_f32,
                                                        const unsigned short* __restrict__ preds_bf,
                                                        float* __restrict__ out) {
    const int gw   = blockIdx.x;        // 0..255 (16-row group)
    const int tid  = threadIdx.x;
    const int wave = tid >> 6;          // 0..7
    const int lane = tid & 63;
    const int l15  = lane & 15;
    const int quad = lane >> 4;
    const int h    = gw >> 7;           // 0: ab, 1: ba
    const int rowbase = gw * 16;
    const unsigned short* Bbase = preds_bf + (size_t)((1 - h) * HALF) * D_K;

    __shared__ float sm[8][16], sl[8][16], sd[8][16];

    // inline gather from fp32 queue: this lane's A-row = queue[argmax(rowbase+l15)]
    unsigned idx = 0xFFFFFFFFu - (unsigned)(amax[rowbase + l15] & 0xFFFFFFFFull);
    const float* arow = queue_f32 + (size_t)idx * D_K;
    bf16x8 a[8];
#pragma unroll
    for (int kc = 0; kc < 8; kc++) {
        float4 f0 = *(const float4*)(arow + kc * 32 + quad * 8);
        float4 f1 = *(const float4*)(arow + kc * 32 + quad * 8 + 4);
        u16x8 t;
        t[0] = f2bf_rn(f0.x); t[1] = f2bf_rn(f0.y); t[2] = f2bf_rn(f0.z); t[3] = f2bf_rn(f0.w);
        t[4] = f2bf_rn(f1.x); t[5] = f2bf_rn(f1.y); t[6] = f2bf_rn(f1.z); t[7] = f2bf_rn(f1.w);
        a[kc] = *(const bf16x8*)&t;
    }

    float m_run[4], l_run[4], diag[4];
#pragma unroll
    for (int r = 0; r < 4; r++) { m_run[r] = -1e30f; l_run[r] = 0.f; diag[r] = -1e30f; }

    const int tdiag = gw & 127;
    for (int tt = 0; tt < 16; tt++) {
        const int t = wave * 16 + tt;
        f32x4 acc0 = (f32x4){0.f, 0.f, 0.f, 0.f};
        f32x4 acc1 = (f32x4){0.f, 0.f, 0.f, 0.f};
#pragma unroll
        for (int kc = 0; kc < 4; kc++) {
            bf16x8 b0 = *(const bf16x8*)&Bbase[(size_t)(t * 16 + l15) * D_K + kc * 32 + quad * 8];
            acc0 = __builtin_amdgcn_mfma_f32_16x16x32_bf16(a[kc], b0, acc0, 0, 0, 0);
            bf16x8 b1 = *(const bf16x8*)&Bbase[(size_t)(t * 16 + l15) * D_K + (kc + 4) * 32 + quad * 8];
            acc1 = __builtin_amdgcn_mfma_f32_16x16x32_bf16(a[kc + 4], b1, acc1, 0, 0, 0);
        }
        f32x4 acc = acc0 + acc1;
#pragma unroll
        for (int reg = 0; reg < 4; reg++) {
            float v = acc[reg] * 10.0f;              // 1/TEMPERATURE
            if (t == tdiag && l15 == quad * 4 + reg) diag[reg] = v;
            float nm = fmaxf(m_run[reg], v);
            l_run[reg] = l_run[reg] * __expf(m_run[reg] - nm) + __expf(v - nm);
            m_run[reg] = nm;
        }
    }
    // 16-lane merge within the wave
#pragma unroll
    for (int reg = 0; reg < 4; reg++) {
#pragma unroll
        for (int m = 1; m < 16; m <<= 1) {
            float om = __shfl_xor(m_run[reg], m, 16);
            float ol = __shfl_xor(l_run[reg], m, 16);
            float od = __shfl_xor(diag[reg], m, 16);
            float nm = fmaxf(m_run[reg], om);
            l_run[reg] = l_run[reg] * __expf(m_run[reg] - nm) + ol * __expf(om - nm);
            m_run[reg] = nm;
            diag[reg] = fmaxf(diag[reg], od);
        }
        if (l15 == 0) {
            sm[wave][quad * 4 + reg] = m_run[reg];
            sl[wave][quad * 4 + reg] = l_run[reg];
            sd[wave][quad * 4 + reg] = diag[reg];
        }
    }
    __syncthreads();
    // cross-wave merge + block-local reduce + single atomic into out
    if (tid < 16) {
        float M = -1e30f, L = 0.f, Dg = -1e30f;
#pragma unroll
        for (int w = 0; w < 8; w++) {
            float mw = sm[w][tid], lw = sl[w][tid], dw = sd[w][tid];
            float nM = fmaxf(M, mw);
            L = L * __expf(M - nM) + lw * __expf(mw - nM);
            M = nM;
            Dg = fmaxf(Dg, dw);
        }
        float rl = (M + __logf(L)) - Dg;
#pragma unroll
        for (int m = 1; m < 16; m <<= 1) rl += __shfl_xor(rl, m, 16);
        if (tid == 0) atomicAdd(out, rl * (1.0f / (float)B_ROWS));
    }
}

extern "C" void kernel_launch(void* const* d_in, const int* in_sizes, int n_in,
                              void* d_out, int out_size, void* d_ws, size_t ws_size,
                              hipStream_t stream) {
    const float* emb   = (const float*)d_in[0];
    const float* preds = (const float*)d_in[1];
    const float* queue = (const float*)d_in[2];

    char* w = (char*)d_ws;
    unsigned long long* amax  = (unsigned long long*)w;                     // 32 KB
    unsigned char*  emb8      = (unsigned char*)(w + (1u << 20));           // 1 MB
    unsigned short* preds_bf  = (unsigned short*)(w + (2u << 20));          // 2 MB
    unsigned char*  queue8    = (unsigned char*)(w + (4u << 20));           // 16 MB

    prep_kernel<<<dim3(PREP_THREADS / 256), 256, 0, stream>>>(
        emb, preds, queue, emb8, preds_bf, queue8, amax, (float*)d_out);
    sim_argmax_kernel<<<dim3((B_ROWS / BM) * (Q_ROWS / (BN * NCHUNK))), 256, 0, stream>>>(
        emb8, queue8, amax);
    logits_ce_kernel<<<dim3(B_ROWS / 16), 512, 0, stream>>>(
        amax, queue, preds_bf, (float*)d_out);
}